// Round 9
// baseline (244.862 us; speedup 1.0000x reference)
//
#include <hip/hip_runtime.h>
#include <stdint.h>

// Ternary CNN, 7 layers, all-NHWC pipeline.
// L0: fp64-exact conv+pool+sign -> NHWC4. L1/L2: dot4 channel-packed convs.
// L3-L6: implicit-GEMM int8 MFMA with v_mfma_i32_32x32x32_i8 (round 9: was
// 16x16x64; 32x32 doubles FLOP/inst and couts served per ds_read_b128 ->
// ~2x fewer LDS reads, MFMAs, waves. r8 showed duration tracks instruction
// count, not HBM traffic). Prepacked A-fragments; LDS-staged input rows
// (planar 16B records, +16B plane pad vs bank conflicts); one barrier.
//
// 32x32x32_i8 mapping: A lane l: m=l&31, k=(l>>5)*16+j. B: n=l&31, same k.
// D: col n=l&31, row m=(reg&3)+8*(reg>>2)+4*(l>>5)  [m74/m101-verified].
// K packs taps (tap-major, ci-minor): k_global = f*32 + (l>>5)*16 + j.
//
// Workspace:
//  A  @ 0        : L0 out NHWC4 4.1MB ; L2 out NHWC16 15.5MB ; L4 out NHWC64 58.0MB
//  B  @ 58491136 : L1 out NHWC8 8.0MB ; L3 out NHWC32 30.0MB ; L5 out NHWC32 28.1MB
//  pA @ 88475904 : packed A-fragments 51200 B (L3@0, L4@5120, L5@23552, L6@41984)

#define DEVINL __device__ __forceinline__
typedef int i32x4  __attribute__((ext_vector_type(4)));
typedef int i32x16 __attribute__((ext_vector_type(16)));

DEVINL int dot4(uint32_t a, uint32_t b, int c) {
#if __has_builtin(__builtin_amdgcn_sdot4)
    return __builtin_amdgcn_sdot4((int)a, (int)b, c, false);
#else
    #pragma unroll
    for (int i = 0; i < 4; ++i)
        c += (int)(int8_t)(a >> (8 * i)) * (int)(int8_t)(b >> (8 * i));
    return c;
#endif
}

DEVINL uint32_t clampb(int v) {           // clamp to [-1,1], return low byte
    v = v > 1 ? 1 : (v < -1 ? -1 : v);
    return (uint32_t)(uint8_t)(int8_t)v;
}

// ---------------- Layer 0: conv(raw fp32, sign(w)) -> maxpool2 -> sign -> NHWC4
__global__ __launch_bounds__(256) void conv0_pool_sign(
    const float* __restrict__ x, const float* __restrict__ w,
    uint32_t* __restrict__ out)
{
    __shared__ float ws[108];
    const int t = threadIdx.x;
    if (t < 108) {
        float v = w[t];
        ws[t] = (v > 0.f) ? 1.f : ((v < 0.f) ? -1.f : 0.f);
    }
    __syncthreads();
    const int idx = blockIdx.x * 256 + t;
    if (idx >= 64 * 127 * 127) return;
    const int px = idx % 127;
    const int py = (idx / 127) % 127;
    const int n  = idx / (127 * 127);

    double acc[4][4];   // [co][pos]
    #pragma unroll
    for (int co = 0; co < 4; ++co)
        #pragma unroll
        for (int p = 0; p < 4; ++p) acc[co][p] = 0.0;

    for (int ci = 0; ci < 3; ++ci) {
        float patch[4][4];
        const float* xp = x + (((size_t)n * 3 + ci) * 256 + 2 * py) * 256 + 2 * px;
        #pragma unroll
        for (int r = 0; r < 4; ++r) {
            const float2* q = (const float2*)(xp + r * 256);
            float2 p01 = q[0], p23 = q[1];
            patch[r][0] = p01.x; patch[r][1] = p01.y;
            patch[r][2] = p23.x; patch[r][3] = p23.y;
        }
        #pragma unroll
        for (int co = 0; co < 4; ++co) {
            const float* wsc = &ws[co * 27 + ci * 9];
            #pragma unroll
            for (int ky = 0; ky < 3; ++ky)
                #pragma unroll
                for (int kx = 0; kx < 3; ++kx) {
                    const double wv = (double)wsc[ky * 3 + kx];
                    acc[co][0] += (double)patch[ky][kx]         * wv;
                    acc[co][1] += (double)patch[ky][kx + 1]     * wv;
                    acc[co][2] += (double)patch[ky + 1][kx]     * wv;
                    acc[co][3] += (double)patch[ky + 1][kx + 1] * wv;
                }
        }
    }
    uint32_t u = 0;
    #pragma unroll
    for (int co = 0; co < 4; ++co) {
        const double m = fmax(fmax(acc[co][0], acc[co][1]), fmax(acc[co][2], acc[co][3]));
        const uint32_t s = (m > 0.0) ? 1u : ((m < 0.0) ? 0xFFu : 0u);
        u |= s << (8 * co);
    }
    out[idx] = u;
}

// ---------------- L1: NHWC4 (127x127) -> NHWC8 (125x125)
__global__ __launch_bounds__(256) void conv_l1(
    const uint32_t* __restrict__ in, const float* __restrict__ w,
    uint2* __restrict__ out)
{
    __shared__ uint32_t pw[72];
    const int t = threadIdx.x;
    if (t < 72) {
        const int co = t / 9, tap = t % 9;
        uint32_t u = 0;
        #pragma unroll
        for (int ci = 0; ci < 4; ++ci) {
            float v = w[(co * 4 + ci) * 9 + tap];
            uint32_t s = (v > 0.f) ? 1u : ((v < 0.f) ? 0xFFu : 0u);
            u |= s << (8 * ci);
        }
        pw[t] = u;
    }
    __syncthreads();

    const int idx = blockIdx.x * 256 + t;   // 64*125*32 = 256000 exact
    const int xg  = idx & 31;
    const int rest = idx >> 5;
    const int py  = rest % 125;
    const int n   = rest / 125;
    int px0 = xg * 4; if (px0 > 121) px0 = 121;

    const uint32_t* base = in + ((size_t)(n * 127 + py) * 127 + px0);
    uint32_t d[3][6];
    #pragma unroll
    for (int r = 0; r < 3; ++r)
        #pragma unroll
        for (int c = 0; c < 6; ++c)
            d[r][c] = base[r * 127 + c];

    int acc[4][8];
    #pragma unroll
    for (int j = 0; j < 4; ++j)
        #pragma unroll
        for (int co = 0; co < 8; ++co) acc[j][co] = 0;

    #pragma unroll
    for (int ky = 0; ky < 3; ++ky)
        #pragma unroll
        for (int kx = 0; kx < 3; ++kx) {
            const int tap = ky * 3 + kx;
            #pragma unroll
            for (int co = 0; co < 8; ++co) {
                const uint32_t wv = pw[co * 9 + tap];
                #pragma unroll
                for (int j = 0; j < 4; ++j)
                    acc[j][co] = dot4(d[ky][j + kx], wv, acc[j][co]);
            }
        }

    uint2* orow = out + ((size_t)(n * 125 + py) * 125 + px0);
    #pragma unroll
    for (int j = 0; j < 4; ++j) {
        uint32_t u0 = 0, u1 = 0;
        #pragma unroll
        for (int co = 0; co < 4; ++co) u0 |= clampb(acc[j][co]) << (8 * co);
        #pragma unroll
        for (int co = 0; co < 4; ++co) u1 |= clampb(acc[j][co + 4]) << (8 * co);
        orow[j] = make_uint2(u0, u1);
    }
}

// ---------------- L2: NHWC8 (125x125) -> NHWC16 (123x123)
__global__ __launch_bounds__(256) void conv_l2(
    const uint32_t* __restrict__ in, const float* __restrict__ w,
    i32x4* __restrict__ out)
{
    __shared__ uint32_t pw[288];
    const int t = threadIdx.x;
    for (int i = t; i < 288; i += 256) {
        const int co = i / 18, r = i % 18, tap = r / 2, half = r % 2;
        uint32_t u = 0;
        #pragma unroll
        for (int ci = 0; ci < 4; ++ci) {
            float v = w[(co * 8 + half * 4 + ci) * 9 + tap];
            uint32_t s = (v > 0.f) ? 1u : ((v < 0.f) ? 0xFFu : 0u);
            u |= s << (8 * ci);
        }
        pw[i] = u;
    }
    __syncthreads();

    const int idx = blockIdx.x * 256 + t;
    if (idx >= 64 * 123 * 31) return;
    const int xg   = idx % 31;
    const int rest = idx / 31;
    const int py   = rest % 123;
    const int n    = rest / 123;
    int px0 = xg * 4; if (px0 > 119) px0 = 119;

    const uint32_t* base = in + ((size_t)(n * 125 + py) * 125 + px0) * 2;
    uint32_t d[3][6][2];
    #pragma unroll
    for (int r = 0; r < 3; ++r)
        #pragma unroll
        for (int c = 0; c < 6; ++c) {
            d[r][c][0] = base[(r * 125 + c) * 2];
            d[r][c][1] = base[(r * 125 + c) * 2 + 1];
        }

    int acc[4][16];
    #pragma unroll
    for (int j = 0; j < 4; ++j)
        #pragma unroll
        for (int co = 0; co < 16; ++co) acc[j][co] = 0;

    #pragma unroll
    for (int ky = 0; ky < 3; ++ky)
        #pragma unroll
        for (int kx = 0; kx < 3; ++kx) {
            const int tap = ky * 3 + kx;
            #pragma unroll
            for (int co = 0; co < 16; ++co) {
                const uint32_t w0 = pw[(co * 9 + tap) * 2];
                const uint32_t w1 = pw[(co * 9 + tap) * 2 + 1];
                #pragma unroll
                for (int j = 0; j < 4; ++j)
                    acc[j][co] = dot4(d[ky][j + kx][1], w1,
                                 dot4(d[ky][j + kx][0], w0, acc[j][co]));
            }
        }

    i32x4* orow = out + ((size_t)(n * 123 + py) * 123 + px0);
    #pragma unroll
    for (int j = 0; j < 4; ++j) {
        uint32_t u[4];
        #pragma unroll
        for (int q = 0; q < 4; ++q) {
            u[q] = 0;
            #pragma unroll
            for (int b = 0; b < 4; ++b)
                u[q] |= clampb(acc[j][q * 4 + b]) << (8 * b);
        }
        orow[j] = (i32x4){(int)u[0], (int)u[1], (int)u[2], (int)u[3]};
    }
}

// ---------------- Prepack A-fragments for 32x32x32 MFMA (runs once, 51200 B).
// Per layer: [ct][f][lane][16B]; lane l: m=l&31 -> co = ct*32 + m;
// k = (l>>5)*16 + j; chunk = 2f + (l>>5); tap = chunk/(CIN/16);
// ci = (chunk%(CIN/16))*16 + j.
__global__ __launch_bounds__(256) void prepack_w(
    const float* __restrict__ w3, const float* __restrict__ w4,
    const float* __restrict__ w5, const float* __restrict__ w6,
    int8_t* __restrict__ pA)
{
    const int idx = blockIdx.x * 256 + threadIdx.x;
    const float* w; int CIN, COUT, NMF, off;
    if      (idx < 5120)  { w = w3; CIN = 16; COUT = 32; NMF = 5;  off = 0; }
    else if (idx < 23552) { w = w4; CIN = 32; COUT = 64; NMF = 9;  off = 5120; }
    else if (idx < 41984) { w = w5; CIN = 64; COUT = 32; NMF = 18; off = 23552; }
    else if (idx < 51200) { w = w6; CIN = 32; COUT = 2;  NMF = 9;  off = 41984; }
    else return;
    const int s   = idx - off;
    const int ct  = s / (NMF * 1024);
    const int r2  = s % (NMF * 1024);
    const int f   = r2 >> 10;
    const int l   = (r2 >> 4) & 63;
    const int j   = r2 & 15;
    const int np  = CIN / 16;
    const int chunk = 2 * f + (l >> 5);
    const int tap = chunk / np;
    const int ci  = (chunk % np) * 16 + j;
    const int co  = ct * 32 + (l & 31);
    int8_t v = 0;
    if (tap < 9 && co < COUT) {
        float x = w[((size_t)co * CIN + ci) * 9 + tap];
        v = (x > 0.f) ? (int8_t)1 : ((x < 0.f) ? (int8_t)(-1) : (int8_t)0);
    }
    pA[idx] = v;
}

// ---------------- L3..L6: implicit-GEMM 32x32x32 i8 MFMA conv, NHWC.
// Block = 64*R threads (R waves = R rows). Each wave: 2 x-tiles of 32 px,
// CT cout-tiles (all COUT). Stage R+2 rows x 66 cols as NP planes of 16B
// records (+16B plane pad), one barrier, then per tile NMF ds_read_b128 +
// CT*NMF MFMAs, clamp+pack epilogue with full-record dword stores.
template <int CIN, int COUT, int CT, int R, int WI, bool FOUT>
__global__ __launch_bounds__(64 * R) void conv_mfma(
    const int8_t* __restrict__ in, const int8_t* __restrict__ packA,
    void* __restrict__ outp, int Wo)
{
    constexpr int NP  = CIN / 16;
    constexpr int NMF = (9 * CIN + 31) / 32;
    constexpr int CB  = 66;
    constexpr int SR  = R + 2;
    constexpr int PST = SR * CB * 16 + 16;   // plane stride, +16B anti-conflict pad
    constexpr int NT  = 64 * R;
    constexpr int NU  = (SR * CB + NT - 1) / NT;
    constexpr int GRP = NMF > 9 ? 9 : NMF;
    __shared__ __align__(16) int8_t lds[NP * PST];

    const int t  = threadIdx.x;
    const int n  = blockIdx.z;
    const int by = blockIdx.y >> 1;
    const int bx = blockIdx.y & 1;
    const int y0 = by * R;
    const int cbase = bx * 64;
    const int ncols = (WI - cbase < CB) ? (WI - cbase) : CB;
    const int npx   = SR * ncols;

    // ---- staging loads: pixel-major full records
    const int8_t* nin = in + (size_t)n * WI * WI * CIN;
    i32x4 st[NU][NP];
    #pragma unroll
    for (int u = 0; u < NU; ++u) {
        int p  = t + u * NT;
        int pp = p < npx ? p : npx - 1;
        int row  = pp / ncols;
        int col  = cbase + pp % ncols;
        int grow = y0 + row; if (grow > WI - 1) grow = WI - 1;
        const int8_t* src = nin + ((size_t)grow * WI + col) * CIN;
        #pragma unroll
        for (int pl = 0; pl < NP; ++pl)
            st[u][pl] = *(const i32x4*)(src + pl * 16);
    }

    // ---- A fragments (prepacked, coalesced, L2-hot)
    const int l = t & 63, wv = t >> 6, h = l >> 5, npix = l & 31;
    i32x4 a[CT][NMF];
    {
        const int8_t* ap = packA + l * 16;
        #pragma unroll
        for (int ct = 0; ct < CT; ++ct)
            #pragma unroll
            for (int f = 0; f < NMF; ++f)
                a[ct][f] = *(const i32x4*)(ap + (ct * NMF + f) * 1024);
    }

    // ---- write staged pixels to LDS planes
    #pragma unroll
    for (int u = 0; u < NU; ++u) {
        int p = t + u * NT;
        if (p < npx) {
            int row = p / ncols, colrel = p % ncols;
            #pragma unroll
            for (int pl = 0; pl < NP; ++pl)
                *(i32x4*)&lds[pl * PST + (row * CB + colrel) * 16] = st[u][pl];
        }
    }
    __syncthreads();

    const int y = y0 + wv;
    if (y >= Wo) return;

    // per-lane LDS offsets per MFMA
    int loff[NMF];
    #pragma unroll
    for (int f = 0; f < NMF; ++f) {
        const int chunk = 2 * f + h;
        const int plane = chunk % NP;
        int tap = chunk / NP;
        if (tap > 8) tap = 8;               // A is zero there; any valid addr
        loff[f] = plane * PST + (((wv + tap / 3) * CB + (tap % 3) + npix) << 4);
    }

    #pragma unroll
    for (int i = 0; i < 2; ++i) {
        int x0 = (bx * 2 + i) * 32;
        if (x0 > Wo - 32) x0 = Wo - 32;
        const int xrel16 = (x0 - cbase) << 4;

        i32x16 acc[CT];
        #pragma unroll
        for (int ct = 0; ct < CT; ++ct)
            acc[ct] = (i32x16){0,0,0,0,0,0,0,0,0,0,0,0,0,0,0,0};

        #pragma unroll
        for (int g0 = 0; g0 < NMF; g0 += GRP) {
            i32x4 bv[GRP];
            #pragma unroll
            for (int f = 0; f < GRP; ++f)
                bv[f] = *(const i32x4*)&lds[loff[g0 + f] + xrel16];
            #pragma unroll
            for (int f = 0; f < GRP; ++f)
                #pragma unroll
                for (int ct = 0; ct < CT; ++ct)
                    acc[ct] = __builtin_amdgcn_mfma_i32_32x32x32_i8(
                        a[ct][g0 + f], bv[f], acc[ct], 0, 0, 0);
        }

        if (!FOUT) {
            uint8_t* base = (uint8_t*)outp
                          + (((size_t)n * Wo + y) * Wo + x0 + npix) * COUT + 4 * h;
            #pragma unroll
            for (int ct = 0; ct < CT; ++ct)
                #pragma unroll
                for (int q = 0; q < 4; ++q) {
                    uint32_t u = clampb(acc[ct][4 * q + 0])
                               | (clampb(acc[ct][4 * q + 1]) << 8)
                               | (clampb(acc[ct][4 * q + 2]) << 16)
                               | (clampb(acc[ct][4 * q + 3]) << 24);
                    *(uint32_t*)(base + ct * 32 + 8 * q) = u;
                }
        } else {
            // COUT=2: m = (reg&3)+8*(reg>>2)+4*h -> only h==0, reg 0..1
            if (h == 0) {
                float* fo = (float*)outp;
                #pragma unroll
                for (int r = 0; r < 2; ++r) {
                    int v = acc[0][r];
                    v = v > 1 ? 1 : (v < -1 ? -1 : v);
                    fo[((size_t)(n * COUT + r) * Wo + y) * Wo + x0 + npix] = (float)v;
                }
            }
        }
    }
}

extern "C" void kernel_launch(void* const* d_in, const int* in_sizes, int n_in,
                              void* d_out, int out_size, void* d_ws, size_t ws_size,
                              hipStream_t stream) {
    const float* x  = (const float*)d_in[0];
    const float* w0 = (const float*)d_in[1];
    const float* w1 = (const float*)d_in[2];
    const float* w2 = (const float*)d_in[3];
    const float* w3 = (const float*)d_in[4];
    const float* w4 = (const float*)d_in[5];
    const float* w5 = (const float*)d_in[6];
    const float* w6 = (const float*)d_in[7];

    int8_t* A  = (int8_t*)d_ws;
    int8_t* B  = A + 58491136;
    int8_t* pA = B + 29984768;

    prepack_w<<<200, 256, 0, stream>>>(w3, w4, w5, w6, pA);

    // L0: (64,3,256,256) fp32 -> NHWC4 (64,127,127,4)
    conv0_pool_sign<<<4033, 256, 0, stream>>>(x, w0, (uint32_t*)A);
    // L1: NHWC4 -> NHWC8 (64,125,125,8)
    conv_l1<<<1000, 256, 0, stream>>>((const uint32_t*)A, w1, (uint2*)B);
    // L2: NHWC8 -> NHWC16 (64,123,123,16)
    conv_l2<<<954, 256, 0, stream>>>((const uint32_t*)B, w2, (i32x4*)A);

    // L3: 16->32, 123 -> 121.  R=8 (512 thr), CT=1, NMF=5, LDS 10.6KB
    conv_mfma<16, 32, 1, 8, 123, false><<<dim3(1, 16 * 2, 64), 512, 0, stream>>>(A, pA + 0, B, 121);
    // L4: 32->64, 121 -> 119.  R=4 (256 thr), CT=2, NMF=9, LDS 12.7KB
    conv_mfma<32, 64, 2, 4, 121, false><<<dim3(1, 30 * 2, 64), 256, 0, stream>>>(B, pA + 5120, A, 119);
    // L5: 64->32, 119 -> 117.  R=4 (256 thr), CT=1, NMF=18, LDS 25.4KB
    conv_mfma<64, 32, 1, 4, 119, false><<<dim3(1, 30 * 2, 64), 256, 0, stream>>>(A, pA + 23552, B, 117);
    // L6: 32->2, 117 -> 115, float NCHW out.  R=4, CT=1, NMF=9, LDS 12.7KB
    conv_mfma<32, 2, 1, 4, 117, true ><<<dim3(1, 29 * 2, 64), 256, 0, stream>>>(B, pA + 41984, d_out, 115);
}

// Round 10
// 213.529 us; speedup vs baseline: 1.1467x; 1.1467x over previous
//
#include <hip/hip_runtime.h>
#include <stdint.h>

// Ternary CNN, 7 layers, all-NHWC pipeline.
// L0: fp64-exact conv+pool+sign -> NHWC4. L1/L2: dot4 channel-packed convs.
// L3-L6: implicit-GEMM v_mfma_i32_32x32x32_i8, prepacked A-fragments,
// LDS-staged input rows.
// Round 10: LDS-TRANSPOSED EPILOGUE. r7-r9 invariant ~50us on L4 traced to
// the D-layout store pattern (each store = 4B into 32 different 64B records
// -> ~32 sector transactions/instr). Now: acc bytes -> LDS [row][px][cout]
// (record stride COUT+4 -> 2 lanes/bank = free), barrier, block-wide dense
// dwordx4 readback stores (4 store instrs/thread, fully contiguous lines).
//
// Workspace:
//  A  @ 0        : L0 out NHWC4 4.1MB ; L2 out NHWC16 15.5MB ; L4 out NHWC64 58.0MB
//  B  @ 58491136 : L1 out NHWC8 8.0MB ; L3 out NHWC32 30.0MB ; L5 out NHWC32 28.1MB
//  pA @ 88475904 : packed A-fragments 51200 B (L3@0, L4@5120, L5@23552, L6@41984)

#define DEVINL __device__ __forceinline__
typedef int i32x4  __attribute__((ext_vector_type(4)));
typedef int i32x16 __attribute__((ext_vector_type(16)));

DEVINL int dot4(uint32_t a, uint32_t b, int c) {
#if __has_builtin(__builtin_amdgcn_sdot4)
    return __builtin_amdgcn_sdot4((int)a, (int)b, c, false);
#else
    #pragma unroll
    for (int i = 0; i < 4; ++i)
        c += (int)(int8_t)(a >> (8 * i)) * (int)(int8_t)(b >> (8 * i));
    return c;
#endif
}

DEVINL uint32_t clampb(int v) {           // clamp to [-1,1], return low byte
    v = v > 1 ? 1 : (v < -1 ? -1 : v);
    return (uint32_t)(uint8_t)(int8_t)v;
}

// ---------------- Layer 0: conv(raw fp32, sign(w)) -> maxpool2 -> sign -> NHWC4
__global__ __launch_bounds__(256) void conv0_pool_sign(
    const float* __restrict__ x, const float* __restrict__ w,
    uint32_t* __restrict__ out)
{
    __shared__ float ws[108];
    const int t = threadIdx.x;
    if (t < 108) {
        float v = w[t];
        ws[t] = (v > 0.f) ? 1.f : ((v < 0.f) ? -1.f : 0.f);
    }
    __syncthreads();
    const int idx = blockIdx.x * 256 + t;
    if (idx >= 64 * 127 * 127) return;
    const int px = idx % 127;
    const int py = (idx / 127) % 127;
    const int n  = idx / (127 * 127);

    double acc[4][4];   // [co][pos]
    #pragma unroll
    for (int co = 0; co < 4; ++co)
        #pragma unroll
        for (int p = 0; p < 4; ++p) acc[co][p] = 0.0;

    for (int ci = 0; ci < 3; ++ci) {
        float patch[4][4];
        const float* xp = x + (((size_t)n * 3 + ci) * 256 + 2 * py) * 256 + 2 * px;
        #pragma unroll
        for (int r = 0; r < 4; ++r) {
            const float2* q = (const float2*)(xp + r * 256);
            float2 p01 = q[0], p23 = q[1];
            patch[r][0] = p01.x; patch[r][1] = p01.y;
            patch[r][2] = p23.x; patch[r][3] = p23.y;
        }
        #pragma unroll
        for (int co = 0; co < 4; ++co) {
            const float* wsc = &ws[co * 27 + ci * 9];
            #pragma unroll
            for (int ky = 0; ky < 3; ++ky)
                #pragma unroll
                for (int kx = 0; kx < 3; ++kx) {
                    const double wv = (double)wsc[ky * 3 + kx];
                    acc[co][0] += (double)patch[ky][kx]         * wv;
                    acc[co][1] += (double)patch[ky][kx + 1]     * wv;
                    acc[co][2] += (double)patch[ky + 1][kx]     * wv;
                    acc[co][3] += (double)patch[ky + 1][kx + 1] * wv;
                }
        }
    }
    uint32_t u = 0;
    #pragma unroll
    for (int co = 0; co < 4; ++co) {
        const double m = fmax(fmax(acc[co][0], acc[co][1]), fmax(acc[co][2], acc[co][3]));
        const uint32_t s = (m > 0.0) ? 1u : ((m < 0.0) ? 0xFFu : 0u);
        u |= s << (8 * co);
    }
    out[idx] = u;
}

// ---------------- L1: NHWC4 (127x127) -> NHWC8 (125x125)
__global__ __launch_bounds__(256) void conv_l1(
    const uint32_t* __restrict__ in, const float* __restrict__ w,
    uint2* __restrict__ out)
{
    __shared__ uint32_t pw[72];
    const int t = threadIdx.x;
    if (t < 72) {
        const int co = t / 9, tap = t % 9;
        uint32_t u = 0;
        #pragma unroll
        for (int ci = 0; ci < 4; ++ci) {
            float v = w[(co * 4 + ci) * 9 + tap];
            uint32_t s = (v > 0.f) ? 1u : ((v < 0.f) ? 0xFFu : 0u);
            u |= s << (8 * ci);
        }
        pw[t] = u;
    }
    __syncthreads();

    const int idx = blockIdx.x * 256 + t;   // 64*125*32 = 256000 exact
    const int xg  = idx & 31;
    const int rest = idx >> 5;
    const int py  = rest % 125;
    const int n   = rest / 125;
    int px0 = xg * 4; if (px0 > 121) px0 = 121;

    const uint32_t* base = in + ((size_t)(n * 127 + py) * 127 + px0);
    uint32_t d[3][6];
    #pragma unroll
    for (int r = 0; r < 3; ++r)
        #pragma unroll
        for (int c = 0; c < 6; ++c)
            d[r][c] = base[r * 127 + c];

    int acc[4][8];
    #pragma unroll
    for (int j = 0; j < 4; ++j)
        #pragma unroll
        for (int co = 0; co < 8; ++co) acc[j][co] = 0;

    #pragma unroll
    for (int ky = 0; ky < 3; ++ky)
        #pragma unroll
        for (int kx = 0; kx < 3; ++kx) {
            const int tap = ky * 3 + kx;
            #pragma unroll
            for (int co = 0; co < 8; ++co) {
                const uint32_t wv = pw[co * 9 + tap];
                #pragma unroll
                for (int j = 0; j < 4; ++j)
                    acc[j][co] = dot4(d[ky][j + kx], wv, acc[j][co]);
            }
        }

    uint2* orow = out + ((size_t)(n * 125 + py) * 125 + px0);
    #pragma unroll
    for (int j = 0; j < 4; ++j) {
        uint32_t u0 = 0, u1 = 0;
        #pragma unroll
        for (int co = 0; co < 4; ++co) u0 |= clampb(acc[j][co]) << (8 * co);
        #pragma unroll
        for (int co = 0; co < 4; ++co) u1 |= clampb(acc[j][co + 4]) << (8 * co);
        orow[j] = make_uint2(u0, u1);
    }
}

// ---------------- L2: NHWC8 (125x125) -> NHWC16 (123x123)
__global__ __launch_bounds__(256) void conv_l2(
    const uint32_t* __restrict__ in, const float* __restrict__ w,
    i32x4* __restrict__ out)
{
    __shared__ uint32_t pw[288];
    const int t = threadIdx.x;
    for (int i = t; i < 288; i += 256) {
        const int co = i / 18, r = i % 18, tap = r / 2, half = r % 2;
        uint32_t u = 0;
        #pragma unroll
        for (int ci = 0; ci < 4; ++ci) {
            float v = w[(co * 8 + half * 4 + ci) * 9 + tap];
            uint32_t s = (v > 0.f) ? 1u : ((v < 0.f) ? 0xFFu : 0u);
            u |= s << (8 * ci);
        }
        pw[i] = u;
    }
    __syncthreads();

    const int idx = blockIdx.x * 256 + t;
    if (idx >= 64 * 123 * 31) return;
    const int xg   = idx % 31;
    const int rest = idx / 31;
    const int py   = rest % 123;
    const int n    = rest / 123;
    int px0 = xg * 4; if (px0 > 119) px0 = 119;

    const uint32_t* base = in + ((size_t)(n * 125 + py) * 125 + px0) * 2;
    uint32_t d[3][6][2];
    #pragma unroll
    for (int r = 0; r < 3; ++r)
        #pragma unroll
        for (int c = 0; c < 6; ++c) {
            d[r][c][0] = base[(r * 125 + c) * 2];
            d[r][c][1] = base[(r * 125 + c) * 2 + 1];
        }

    int acc[4][16];
    #pragma unroll
    for (int j = 0; j < 4; ++j)
        #pragma unroll
        for (int co = 0; co < 16; ++co) acc[j][co] = 0;

    #pragma unroll
    for (int ky = 0; ky < 3; ++ky)
        #pragma unroll
        for (int kx = 0; kx < 3; ++kx) {
            const int tap = ky * 3 + kx;
            #pragma unroll
            for (int co = 0; co < 16; ++co) {
                const uint32_t w0 = pw[(co * 9 + tap) * 2];
                const uint32_t w1 = pw[(co * 9 + tap) * 2 + 1];
                #pragma unroll
                for (int j = 0; j < 4; ++j)
                    acc[j][co] = dot4(d[ky][j + kx][1], w1,
                                 dot4(d[ky][j + kx][0], w0, acc[j][co]));
            }
        }

    i32x4* orow = out + ((size_t)(n * 123 + py) * 123 + px0);
    #pragma unroll
    for (int j = 0; j < 4; ++j) {
        uint32_t u[4];
        #pragma unroll
        for (int q = 0; q < 4; ++q) {
            u[q] = 0;
            #pragma unroll
            for (int b = 0; b < 4; ++b)
                u[q] |= clampb(acc[j][q * 4 + b]) << (8 * b);
        }
        orow[j] = (i32x4){(int)u[0], (int)u[1], (int)u[2], (int)u[3]};
    }
}

// ---------------- Prepack A-fragments for 32x32x32 MFMA (runs once, 51200 B).
__global__ __launch_bounds__(256) void prepack_w(
    const float* __restrict__ w3, const float* __restrict__ w4,
    const float* __restrict__ w5, const float* __restrict__ w6,
    int8_t* __restrict__ pA)
{
    const int idx = blockIdx.x * 256 + threadIdx.x;
    const float* w; int CIN, COUT, NMF, off;
    if      (idx < 5120)  { w = w3; CIN = 16; COUT = 32; NMF = 5;  off = 0; }
    else if (idx < 23552) { w = w4; CIN = 32; COUT = 64; NMF = 9;  off = 5120; }
    else if (idx < 41984) { w = w5; CIN = 64; COUT = 32; NMF = 18; off = 23552; }
    else if (idx < 51200) { w = w6; CIN = 32; COUT = 2;  NMF = 9;  off = 41984; }
    else return;
    const int s   = idx - off;
    const int ct  = s / (NMF * 1024);
    const int r2  = s % (NMF * 1024);
    const int f   = r2 >> 10;
    const int l   = (r2 >> 4) & 63;
    const int j   = r2 & 15;
    const int np  = CIN / 16;
    const int chunk = 2 * f + (l >> 5);
    const int tap = chunk / np;
    const int ci  = (chunk % np) * 16 + j;
    const int co  = ct * 32 + (l & 31);
    int8_t v = 0;
    if (tap < 9 && co < COUT) {
        float x = w[((size_t)co * CIN + ci) * 9 + tap];
        v = (x > 0.f) ? (int8_t)1 : ((x < 0.f) ? (int8_t)(-1) : (int8_t)0);
    }
    pA[idx] = v;
}

// ---------------- L3..L6: implicit-GEMM 32x32x32 i8 MFMA conv, NHWC.
// Block = 64*R threads. Waves = rows. Stage R+2 rows x 66 cols as NP planes
// (+16B plane pad). MFMAs feed from ds_read_b128. Epilogue (non-FOUT):
// acc bytes -> LDS transpose region [row][px][cout] (record stride COUT+4 ->
// write = exactly 2 lanes/bank), barrier, dense dwordx4 readback stores.
template <int CIN, int COUT, int CT, int R, int WI, bool FOUT>
__global__ __launch_bounds__(64 * R) void conv_mfma(
    const int8_t* __restrict__ in, const int8_t* __restrict__ packA,
    void* __restrict__ outp, int Wo)
{
    constexpr int NP  = CIN / 16;
    constexpr int NMF = (9 * CIN + 31) / 32;
    constexpr int CB  = 66;
    constexpr int SR  = R + 2;
    constexpr int PST = SR * CB * 16 + 16;   // staging plane stride (+16B pad)
    constexpr int NT  = 64 * R;
    constexpr int NU  = (SR * CB + NT - 1) / NT;
    constexpr int GRP = NMF > 9 ? 9 : NMF;
    constexpr int REC = COUT + 4;            // transpose record stride
    constexpr int OUTB = FOUT ? 0 : R * 64 * REC;
    __shared__ __align__(16) int8_t lds[NP * PST + OUTB];

    const int t  = threadIdx.x;
    const int n  = blockIdx.z;
    const int by = blockIdx.y >> 1;
    const int bx = blockIdx.y & 1;
    const int y0 = by * R;
    const int cbase = bx * 64;
    const int ncols = (WI - cbase < CB) ? (WI - cbase) : CB;
    const int npx   = SR * ncols;

    // ---- staging loads: pixel-major full records
    const int8_t* nin = in + (size_t)n * WI * WI * CIN;
    i32x4 st[NU][NP];
    #pragma unroll
    for (int u = 0; u < NU; ++u) {
        int p  = t + u * NT;
        int pp = p < npx ? p : npx - 1;
        int row  = pp / ncols;
        int col  = cbase + pp % ncols;
        int grow = y0 + row; if (grow > WI - 1) grow = WI - 1;
        const int8_t* src = nin + ((size_t)grow * WI + col) * CIN;
        #pragma unroll
        for (int pl = 0; pl < NP; ++pl)
            st[u][pl] = *(const i32x4*)(src + pl * 16);
    }

    // ---- A fragments (prepacked, coalesced, L2-hot)
    const int l = t & 63, wv = t >> 6, h = l >> 5, npix = l & 31;
    i32x4 a[CT][NMF];
    {
        const int8_t* ap = packA + l * 16;
        #pragma unroll
        for (int ct = 0; ct < CT; ++ct)
            #pragma unroll
            for (int f = 0; f < NMF; ++f)
                a[ct][f] = *(const i32x4*)(ap + (ct * NMF + f) * 1024);
    }

    // ---- write staged pixels to LDS planes
    #pragma unroll
    for (int u = 0; u < NU; ++u) {
        int p = t + u * NT;
        if (p < npx) {
            int row = p / ncols, colrel = p % ncols;
            #pragma unroll
            for (int pl = 0; pl < NP; ++pl)
                *(i32x4*)&lds[pl * PST + (row * CB + colrel) * 16] = st[u][pl];
        }
    }
    __syncthreads();

    // per-lane LDS offsets per MFMA
    int loff[NMF];
    #pragma unroll
    for (int f = 0; f < NMF; ++f) {
        const int chunk = 2 * f + h;
        const int plane = chunk % NP;
        int tap = chunk / NP;
        if (tap > 8) tap = 8;               // A is zero there; any valid addr
        loff[f] = plane * PST + (((wv + tap / 3) * CB + (tap % 3) + npix) << 4);
    }

    int8_t* outr = &lds[NP * PST];          // transpose region

    #pragma unroll
    for (int i = 0; i < 2; ++i) {
        int x0 = (bx * 2 + i) * 32;
        if (x0 > Wo - 32) x0 = Wo - 32;
        const int xrel16 = (x0 - cbase) << 4;

        i32x16 acc[CT];
        #pragma unroll
        for (int ct = 0; ct < CT; ++ct)
            acc[ct] = (i32x16){0,0,0,0,0,0,0,0,0,0,0,0,0,0,0,0};

        #pragma unroll
        for (int g0 = 0; g0 < NMF; g0 += GRP) {
            i32x4 bv[GRP];
            #pragma unroll
            for (int f = 0; f < GRP; ++f)
                bv[f] = *(const i32x4*)&lds[loff[g0 + f] + xrel16];
            #pragma unroll
            for (int f = 0; f < GRP; ++f)
                #pragma unroll
                for (int ct = 0; ct < CT; ++ct)
                    acc[ct] = __builtin_amdgcn_mfma_i32_32x32x32_i8(
                        a[ct][g0 + f], bv[f], acc[ct], 0, 0, 0);
        }

        if (!FOUT) {
            // transpose: lane holds 16 couts (m = 8q+4h+b, +32ct) of pixel
            // pxb = x0-cbase+npix, row wrow=wv. 2 lanes/bank -> conflict-free.
            const int pxb = x0 - cbase + npix;
            uint32_t* dst = (uint32_t*)&outr[(wv * 64 + pxb) * REC + 4 * h];
            #pragma unroll
            for (int ct = 0; ct < CT; ++ct)
                #pragma unroll
                for (int q = 0; q < 4; ++q) {
                    uint32_t u = clampb(acc[ct][4 * q + 0])
                               | (clampb(acc[ct][4 * q + 1]) << 8)
                               | (clampb(acc[ct][4 * q + 2]) << 16)
                               | (clampb(acc[ct][4 * q + 3]) << 24);
                    dst[ct * 8 + 2 * q] = u;
                }
        } else {
            // COUT=2: m = (reg&3)+8*(reg>>2)+4*h -> only h==0, reg 0..1
            const int y = y0 + wv;
            if (h == 0 && y < Wo) {
                float* fo = (float*)outp;
                #pragma unroll
                for (int r = 0; r < 2; ++r) {
                    int v = acc[0][r];
                    v = v > 1 ? 1 : (v < -1 ? -1 : v);
                    fo[((size_t)(n * COUT + r) * Wo + y) * Wo + x0 + npix] = (float)v;
                }
            }
        }
    }

    if (!FOUT) {
        __syncthreads();
        // dense readback: chunk c -> row r, pixel p, 16B piece k; lanes
        // consecutive in (p,k) -> fully contiguous dwordx4 store lines.
        constexpr int CPR = 64 * COUT / 16;            // 16B chunks per row
        constexpr int NIT = (R * CPR) / NT;            // exact for all layers
        uint8_t* gbase = (uint8_t*)outp;
        #pragma unroll
        for (int it = 0; it < NIT; ++it) {
            const int c = it * NT + t;
            const int r = c / CPR, wi = c % CPR;
            const int p = wi / (COUT / 16), k = wi % (COUT / 16);
            const int gy = y0 + r, gx = cbase + p;
            if (gy < Wo && gx < Wo) {
                const uint8_t* src = (const uint8_t*)&outr[(r * 64 + p) * REC + k * 16];
                uint32_t v0 = *(const uint32_t*)(src + 0);
                uint32_t v1 = *(const uint32_t*)(src + 4);
                uint32_t v2 = *(const uint32_t*)(src + 8);
                uint32_t v3 = *(const uint32_t*)(src + 12);
                *(i32x4*)(gbase + (((size_t)n * Wo + gy) * Wo + gx) * COUT + k * 16)
                    = (i32x4){(int)v0, (int)v1, (int)v2, (int)v3};
            }
        }
    }
}

extern "C" void kernel_launch(void* const* d_in, const int* in_sizes, int n_in,
                              void* d_out, int out_size, void* d_ws, size_t ws_size,
                              hipStream_t stream) {
    const float* x  = (const float*)d_in[0];
    const float* w0 = (const float*)d_in[1];
    const float* w1 = (const float*)d_in[2];
    const float* w2 = (const float*)d_in[3];
    const float* w3 = (const float*)d_in[4];
    const float* w4 = (const float*)d_in[5];
    const float* w5 = (const float*)d_in[6];
    const float* w6 = (const float*)d_in[7];

    int8_t* A  = (int8_t*)d_ws;
    int8_t* B  = A + 58491136;
    int8_t* pA = B + 29984768;

    prepack_w<<<200, 256, 0, stream>>>(w3, w4, w5, w6, pA);

    // L0: (64,3,256,256) fp32 -> NHWC4 (64,127,127,4)
    conv0_pool_sign<<<4033, 256, 0, stream>>>(x, w0, (uint32_t*)A);
    // L1: NHWC4 -> NHWC8 (64,125,125,8)
    conv_l1<<<1000, 256, 0, stream>>>((const uint32_t*)A, w1, (uint2*)B);
    // L2: NHWC8 -> NHWC16 (64,123,123,16)
    conv_l2<<<954, 256, 0, stream>>>((const uint32_t*)B, w2, (i32x4*)A);

    // L3: 16->32, 123 -> 121.  R=8 (512 thr), CT=1, NMF=5, LDS ~29KB
    conv_mfma<16, 32, 1, 8, 123, false><<<dim3(1, 16 * 2, 64), 512, 0, stream>>>(A, pA + 0, B, 121);
    // L4: 32->64, 121 -> 119.  R=4 (256 thr), CT=2, NMF=9, LDS ~30KB
    conv_mfma<32, 64, 2, 4, 121, false><<<dim3(1, 30 * 2, 64), 256, 0, stream>>>(B, pA + 5120, A, 119);
    // L5: 64->32, 119 -> 117.  R=4 (256 thr), CT=1, NMF=18, LDS ~35KB
    conv_mfma<64, 32, 1, 4, 119, false><<<dim3(1, 30 * 2, 64), 256, 0, stream>>>(A, pA + 23552, B, 117);
    // L6: 32->2, 117 -> 115, float NCHW out.  R=4, CT=1, NMF=9, LDS ~12.7KB
    conv_mfma<32, 2, 1, 4, 117, true ><<<dim3(1, 29 * 2, 64), 256, 0, stream>>>(B, pA + 41984, d_out, 115);
}

// Round 11
// 201.244 us; speedup vs baseline: 1.2167x; 1.0610x over previous
//
#include <hip/hip_runtime.h>
#include <stdint.h>

// Ternary CNN, 7 layers, all-NHWC pipeline.
// L0 (round 11): fp32 main path + rigorous error bound + rare fp64
//   escalation (bit-exact r7-r10 operation order) for |pooled max| <= bound.
//   fp64 FMA is half-rate on CDNA4; escalation hits ~0.4% of waves.
// L1/L2: dot4 channel-packed convs. L3-L6: implicit-GEMM v_mfma_i32_32x32x32_i8,
// prepacked A-fragments, LDS-staged input, LDS-transposed dense epilogue (r10).
//
// Workspace:
//  A  @ 0        : L0 out NHWC4 4.1MB ; L2 out NHWC16 15.5MB ; L4 out NHWC64 58.0MB
//  B  @ 58491136 : L1 out NHWC8 8.0MB ; L3 out NHWC32 30.0MB ; L5 out NHWC32 28.1MB
//  pA @ 88475904 : packed A-fragments 51200 B (L3@0, L4@5120, L5@23552, L6@41984)

#define DEVINL __device__ __forceinline__
typedef int   i32x4  __attribute__((ext_vector_type(4)));
typedef int   i32x16 __attribute__((ext_vector_type(16)));
typedef float f32x2  __attribute__((ext_vector_type(2)));

DEVINL int dot4(uint32_t a, uint32_t b, int c) {
#if __has_builtin(__builtin_amdgcn_sdot4)
    return __builtin_amdgcn_sdot4((int)a, (int)b, c, false);
#else
    #pragma unroll
    for (int i = 0; i < 4; ++i)
        c += (int)(int8_t)(a >> (8 * i)) * (int)(int8_t)(b >> (8 * i));
    return c;
#endif
}

DEVINL uint32_t clampb(int v) {           // clamp to [-1,1], return low byte
    v = v > 1 ? 1 : (v < -1 ? -1 : v);
    return (uint32_t)(uint8_t)(int8_t)v;
}

// ---------------- Layer 0: conv(raw fp32, sign(w)) -> maxpool2 -> sign -> NHWC4
// fp32 fast path with error bound; fp64 escalation replicates r7-r10 order.
__global__ __launch_bounds__(256) void conv0_pool_sign(
    const float* __restrict__ x, const float* __restrict__ w,
    uint32_t* __restrict__ out)
{
    __shared__ float ws[108];
    const int t = threadIdx.x;
    if (t < 108) {
        float v = w[t];
        ws[t] = (v > 0.f) ? 1.f : ((v < 0.f) ? -1.f : 0.f);
    }
    __syncthreads();
    const int idx = blockIdx.x * 256 + t;
    if (idx >= 64 * 127 * 127) return;
    const int px = idx % 127;
    const int py = (idx / 127) % 127;
    const int n  = idx / (127 * 127);

    // Load all 3 channels' 4x4 patches up-front (24 float2 loads, all in flight).
    float patch[3][4][4];
    #pragma unroll
    for (int ci = 0; ci < 3; ++ci) {
        const float* xp = x + (((size_t)n * 3 + ci) * 256 + 2 * py) * 256 + 2 * px;
        #pragma unroll
        for (int r = 0; r < 4; ++r) {
            const float2* q = (const float2*)(xp + r * 256);
            float2 p01 = q[0], p23 = q[1];
            patch[ci][r][0] = p01.x; patch[ci][r][1] = p01.y;
            patch[ci][r][2] = p23.x; patch[ci][r][3] = p23.y;
        }
    }

    // fp32 accumulation (positions paired: A={pos0,pos1} row ky, B={pos2,pos3} row ky+1).
    f32x2 accA[4], accB[4];
    #pragma unroll
    for (int co = 0; co < 4; ++co) { accA[co] = (f32x2){0.f, 0.f}; accB[co] = (f32x2){0.f, 0.f}; }

    #pragma unroll
    for (int ci = 0; ci < 3; ++ci)
        #pragma unroll
        for (int co = 0; co < 4; ++co) {
            const float* wsc = &ws[co * 27 + ci * 9];
            #pragma unroll
            for (int ky = 0; ky < 3; ++ky)
                #pragma unroll
                for (int kx = 0; kx < 3; ++kx) {
                    const float wv = wsc[ky * 3 + kx];
                    f32x2 p0 = (f32x2){patch[ci][ky][kx],     patch[ci][ky][kx + 1]};
                    f32x2 p1 = (f32x2){patch[ci][ky + 1][kx], patch[ci][ky + 1][kx + 1]};
                    accA[co] += p0 * wv;
                    accB[co] += p1 * wv;
                }
        }

    // Error bound: 27 sequential fp32 adds of terms with sum(|terms|) <= S.
    float S = 0.f;
    #pragma unroll
    for (int ci = 0; ci < 3; ++ci)
        #pragma unroll
        for (int r = 0; r < 4; ++r)
            #pragma unroll
            for (int c = 0; c < 4; ++c)
                S += fabsf(patch[ci][r][c]);
    const float bound = 4e-6f * S + 1e-6f;   // ~25x margin over 27*eps*S

    uint32_t u = 0;
    bool esc = false;
    #pragma unroll
    for (int co = 0; co < 4; ++co) {
        const float m = fmaxf(fmaxf(accA[co].x, accA[co].y),
                              fmaxf(accB[co].x, accB[co].y));
        if (fabsf(m) <= bound) esc = true;
        u |= ((m > 0.f) ? 1u : 0xFFu) << (8 * co);
    }

    if (esc) {
        // fp64 recompute, operation order bit-identical to r7-r10 kernels.
        double acc[4][4];
        #pragma unroll
        for (int co = 0; co < 4; ++co)
            #pragma unroll
            for (int p = 0; p < 4; ++p) acc[co][p] = 0.0;
        #pragma unroll
        for (int ci = 0; ci < 3; ++ci)
            #pragma unroll
            for (int co = 0; co < 4; ++co) {
                const float* wsc = &ws[co * 27 + ci * 9];
                #pragma unroll
                for (int ky = 0; ky < 3; ++ky)
                    #pragma unroll
                    for (int kx = 0; kx < 3; ++kx) {
                        const double wv = (double)wsc[ky * 3 + kx];
                        acc[co][0] += (double)patch[ci][ky][kx]         * wv;
                        acc[co][1] += (double)patch[ci][ky][kx + 1]     * wv;
                        acc[co][2] += (double)patch[ci][ky + 1][kx]     * wv;
                        acc[co][3] += (double)patch[ci][ky + 1][kx + 1] * wv;
                    }
            }
        u = 0;
        #pragma unroll
        for (int co = 0; co < 4; ++co) {
            const double m = fmax(fmax(acc[co][0], acc[co][1]), fmax(acc[co][2], acc[co][3]));
            const uint32_t s = (m > 0.0) ? 1u : ((m < 0.0) ? 0xFFu : 0u);
            u |= s << (8 * co);
        }
    }
    out[idx] = u;
}

// ---------------- L1: NHWC4 (127x127) -> NHWC8 (125x125)
__global__ __launch_bounds__(256) void conv_l1(
    const uint32_t* __restrict__ in, const float* __restrict__ w,
    uint2* __restrict__ out)
{
    __shared__ uint32_t pw[72];
    const int t = threadIdx.x;
    if (t < 72) {
        const int co = t / 9, tap = t % 9;
        uint32_t u = 0;
        #pragma unroll
        for (int ci = 0; ci < 4; ++ci) {
            float v = w[(co * 4 + ci) * 9 + tap];
            uint32_t s = (v > 0.f) ? 1u : ((v < 0.f) ? 0xFFu : 0u);
            u |= s << (8 * ci);
        }
        pw[t] = u;
    }
    __syncthreads();

    const int idx = blockIdx.x * 256 + t;   // 64*125*32 = 256000 exact
    const int xg  = idx & 31;
    const int rest = idx >> 5;
    const int py  = rest % 125;
    const int n   = rest / 125;
    int px0 = xg * 4; if (px0 > 121) px0 = 121;

    const uint32_t* base = in + ((size_t)(n * 127 + py) * 127 + px0);
    uint32_t d[3][6];
    #pragma unroll
    for (int r = 0; r < 3; ++r)
        #pragma unroll
        for (int c = 0; c < 6; ++c)
            d[r][c] = base[r * 127 + c];

    int acc[4][8];
    #pragma unroll
    for (int j = 0; j < 4; ++j)
        #pragma unroll
        for (int co = 0; co < 8; ++co) acc[j][co] = 0;

    #pragma unroll
    for (int ky = 0; ky < 3; ++ky)
        #pragma unroll
        for (int kx = 0; kx < 3; ++kx) {
            const int tap = ky * 3 + kx;
            #pragma unroll
            for (int co = 0; co < 8; ++co) {
                const uint32_t wv = pw[co * 9 + tap];
                #pragma unroll
                for (int j = 0; j < 4; ++j)
                    acc[j][co] = dot4(d[ky][j + kx], wv, acc[j][co]);
            }
        }

    uint2* orow = out + ((size_t)(n * 125 + py) * 125 + px0);
    #pragma unroll
    for (int j = 0; j < 4; ++j) {
        uint32_t u0 = 0, u1 = 0;
        #pragma unroll
        for (int co = 0; co < 4; ++co) u0 |= clampb(acc[j][co]) << (8 * co);
        #pragma unroll
        for (int co = 0; co < 4; ++co) u1 |= clampb(acc[j][co + 4]) << (8 * co);
        orow[j] = make_uint2(u0, u1);
    }
}

// ---------------- L2: NHWC8 (125x125) -> NHWC16 (123x123)
__global__ __launch_bounds__(256) void conv_l2(
    const uint32_t* __restrict__ in, const float* __restrict__ w,
    i32x4* __restrict__ out)
{
    __shared__ uint32_t pw[288];
    const int t = threadIdx.x;
    for (int i = t; i < 288; i += 256) {
        const int co = i / 18, r = i % 18, tap = r / 2, half = r % 2;
        uint32_t u = 0;
        #pragma unroll
        for (int ci = 0; ci < 4; ++ci) {
            float v = w[(co * 8 + half * 4 + ci) * 9 + tap];
            uint32_t s = (v > 0.f) ? 1u : ((v < 0.f) ? 0xFFu : 0u);
            u |= s << (8 * ci);
        }
        pw[i] = u;
    }
    __syncthreads();

    const int idx = blockIdx.x * 256 + t;
    if (idx >= 64 * 123 * 31) return;
    const int xg   = idx % 31;
    const int rest = idx / 31;
    const int py   = rest % 123;
    const int n    = rest / 123;
    int px0 = xg * 4; if (px0 > 119) px0 = 119;

    const uint32_t* base = in + ((size_t)(n * 125 + py) * 125 + px0) * 2;
    uint32_t d[3][6][2];
    #pragma unroll
    for (int r = 0; r < 3; ++r)
        #pragma unroll
        for (int c = 0; c < 6; ++c) {
            d[r][c][0] = base[(r * 125 + c) * 2];
            d[r][c][1] = base[(r * 125 + c) * 2 + 1];
        }

    int acc[4][16];
    #pragma unroll
    for (int j = 0; j < 4; ++j)
        #pragma unroll
        for (int co = 0; co < 16; ++co) acc[j][co] = 0;

    #pragma unroll
    for (int ky = 0; ky < 3; ++ky)
        #pragma unroll
        for (int kx = 0; kx < 3; ++kx) {
            const int tap = ky * 3 + kx;
            #pragma unroll
            for (int co = 0; co < 16; ++co) {
                const uint32_t w0 = pw[(co * 9 + tap) * 2];
                const uint32_t w1 = pw[(co * 9 + tap) * 2 + 1];
                #pragma unroll
                for (int j = 0; j < 4; ++j)
                    acc[j][co] = dot4(d[ky][j + kx][1], w1,
                                 dot4(d[ky][j + kx][0], w0, acc[j][co]));
            }
        }

    i32x4* orow = out + ((size_t)(n * 123 + py) * 123 + px0);
    #pragma unroll
    for (int j = 0; j < 4; ++j) {
        uint32_t u[4];
        #pragma unroll
        for (int q = 0; q < 4; ++q) {
            u[q] = 0;
            #pragma unroll
            for (int b = 0; b < 4; ++b)
                u[q] |= clampb(acc[j][q * 4 + b]) << (8 * b);
        }
        orow[j] = (i32x4){(int)u[0], (int)u[1], (int)u[2], (int)u[3]};
    }
}

// ---------------- Prepack A-fragments for 32x32x32 MFMA (runs once, 51200 B).
__global__ __launch_bounds__(256) void prepack_w(
    const float* __restrict__ w3, const float* __restrict__ w4,
    const float* __restrict__ w5, const float* __restrict__ w6,
    int8_t* __restrict__ pA)
{
    const int idx = blockIdx.x * 256 + threadIdx.x;
    const float* w; int CIN, COUT, NMF, off;
    if      (idx < 5120)  { w = w3; CIN = 16; COUT = 32; NMF = 5;  off = 0; }
    else if (idx < 23552) { w = w4; CIN = 32; COUT = 64; NMF = 9;  off = 5120; }
    else if (idx < 41984) { w = w5; CIN = 64; COUT = 32; NMF = 18; off = 23552; }
    else if (idx < 51200) { w = w6; CIN = 32; COUT = 2;  NMF = 9;  off = 41984; }
    else return;
    const int s   = idx - off;
    const int ct  = s / (NMF * 1024);
    const int r2  = s % (NMF * 1024);
    const int f   = r2 >> 10;
    const int l   = (r2 >> 4) & 63;
    const int j   = r2 & 15;
    const int np  = CIN / 16;
    const int chunk = 2 * f + (l >> 5);
    const int tap = chunk / np;
    const int ci  = (chunk % np) * 16 + j;
    const int co  = ct * 32 + (l & 31);
    int8_t v = 0;
    if (tap < 9 && co < COUT) {
        float x = w[((size_t)co * CIN + ci) * 9 + tap];
        v = (x > 0.f) ? (int8_t)1 : ((x < 0.f) ? (int8_t)(-1) : (int8_t)0);
    }
    pA[idx] = v;
}

// ---------------- L3..L6: implicit-GEMM 32x32x32 i8 MFMA conv, NHWC.
// Block = 64*R threads. Waves = rows. Stage R+2 rows x 66 cols as NP planes
// (+16B plane pad). MFMAs feed from ds_read_b128. Epilogue (non-FOUT):
// acc bytes -> LDS transpose region [row][px][cout] (record stride COUT+4 ->
// write = exactly 2 lanes/bank), barrier, dense dwordx4 readback stores.
template <int CIN, int COUT, int CT, int R, int WI, bool FOUT>
__global__ __launch_bounds__(64 * R) void conv_mfma(
    const int8_t* __restrict__ in, const int8_t* __restrict__ packA,
    void* __restrict__ outp, int Wo)
{
    constexpr int NP  = CIN / 16;
    constexpr int NMF = (9 * CIN + 31) / 32;
    constexpr int CB  = 66;
    constexpr int SR  = R + 2;
    constexpr int PST = SR * CB * 16 + 16;   // staging plane stride (+16B pad)
    constexpr int NT  = 64 * R;
    constexpr int NU  = (SR * CB + NT - 1) / NT;
    constexpr int GRP = NMF > 9 ? 9 : NMF;
    constexpr int REC = COUT + 4;            // transpose record stride
    constexpr int OUTB = FOUT ? 0 : R * 64 * REC;
    __shared__ __align__(16) int8_t lds[NP * PST + OUTB];

    const int t  = threadIdx.x;
    const int n  = blockIdx.z;
    const int by = blockIdx.y >> 1;
    const int bx = blockIdx.y & 1;
    const int y0 = by * R;
    const int cbase = bx * 64;
    const int ncols = (WI - cbase < CB) ? (WI - cbase) : CB;
    const int npx   = SR * ncols;

    // ---- staging loads: pixel-major full records
    const int8_t* nin = in + (size_t)n * WI * WI * CIN;
    i32x4 st[NU][NP];
    #pragma unroll
    for (int u = 0; u < NU; ++u) {
        int p  = t + u * NT;
        int pp = p < npx ? p : npx - 1;
        int row  = pp / ncols;
        int col  = cbase + pp % ncols;
        int grow = y0 + row; if (grow > WI - 1) grow = WI - 1;
        const int8_t* src = nin + ((size_t)grow * WI + col) * CIN;
        #pragma unroll
        for (int pl = 0; pl < NP; ++pl)
            st[u][pl] = *(const i32x4*)(src + pl * 16);
    }

    // ---- A fragments (prepacked, coalesced, L2-hot)
    const int l = t & 63, wv = t >> 6, h = l >> 5, npix = l & 31;
    i32x4 a[CT][NMF];
    {
        const int8_t* ap = packA + l * 16;
        #pragma unroll
        for (int ct = 0; ct < CT; ++ct)
            #pragma unroll
            for (int f = 0; f < NMF; ++f)
                a[ct][f] = *(const i32x4*)(ap + (ct * NMF + f) * 1024);
    }

    // ---- write staged pixels to LDS planes
    #pragma unroll
    for (int u = 0; u < NU; ++u) {
        int p = t + u * NT;
        if (p < npx) {
            int row = p / ncols, colrel = p % ncols;
            #pragma unroll
            for (int pl = 0; pl < NP; ++pl)
                *(i32x4*)&lds[pl * PST + (row * CB + colrel) * 16] = st[u][pl];
        }
    }
    __syncthreads();

    // per-lane LDS offsets per MFMA
    int loff[NMF];
    #pragma unroll
    for (int f = 0; f < NMF; ++f) {
        const int chunk = 2 * f + h;
        const int plane = chunk % NP;
        int tap = chunk / NP;
        if (tap > 8) tap = 8;               // A is zero there; any valid addr
        loff[f] = plane * PST + (((wv + tap / 3) * CB + (tap % 3) + npix) << 4);
    }

    int8_t* outr = &lds[NP * PST];          // transpose region

    #pragma unroll
    for (int i = 0; i < 2; ++i) {
        int x0 = (bx * 2 + i) * 32;
        if (x0 > Wo - 32) x0 = Wo - 32;
        const int xrel16 = (x0 - cbase) << 4;

        i32x16 acc[CT];
        #pragma unroll
        for (int ct = 0; ct < CT; ++ct)
            acc[ct] = (i32x16){0,0,0,0,0,0,0,0,0,0,0,0,0,0,0,0};

        #pragma unroll
        for (int g0 = 0; g0 < NMF; g0 += GRP) {
            i32x4 bv[GRP];
            #pragma unroll
            for (int f = 0; f < GRP; ++f)
                bv[f] = *(const i32x4*)&lds[loff[g0 + f] + xrel16];
            #pragma unroll
            for (int f = 0; f < GRP; ++f)
                #pragma unroll
                for (int ct = 0; ct < CT; ++ct)
                    acc[ct] = __builtin_amdgcn_mfma_i32_32x32x32_i8(
                        a[ct][g0 + f], bv[f], acc[ct], 0, 0, 0);
        }

        if (!FOUT) {
            // transpose: lane holds 16 couts (m = 8q+4h+b, +32ct) of pixel
            // pxb = x0-cbase+npix, row wv. 2 lanes/bank -> conflict-free.
            const int pxb = x0 - cbase + npix;
            uint32_t* dst = (uint32_t*)&outr[(wv * 64 + pxb) * REC + 4 * h];
            #pragma unroll
            for (int ct = 0; ct < CT; ++ct)
                #pragma unroll
                for (int q = 0; q < 4; ++q) {
                    uint32_t u = clampb(acc[ct][4 * q + 0])
                               | (clampb(acc[ct][4 * q + 1]) << 8)
                               | (clampb(acc[ct][4 * q + 2]) << 16)
                               | (clampb(acc[ct][4 * q + 3]) << 24);
                    dst[ct * 8 + 2 * q] = u;
                }
        } else {
            // COUT=2: m = (reg&3)+8*(reg>>2)+4*h -> only h==0, reg 0..1
            const int y = y0 + wv;
            if (h == 0 && y < Wo) {
                float* fo = (float*)outp;
                #pragma unroll
                for (int r = 0; r < 2; ++r) {
                    int v = acc[0][r];
                    v = v > 1 ? 1 : (v < -1 ? -1 : v);
                    fo[((size_t)(n * COUT + r) * Wo + y) * Wo + x0 + npix] = (float)v;
                }
            }
        }
    }

    if (!FOUT) {
        __syncthreads();
        // dense readback: chunk c -> row r, pixel p, 16B piece k; lanes
        // consecutive in (p,k) -> fully contiguous dwordx4 store lines.
        constexpr int CPR = 64 * COUT / 16;            // 16B chunks per row
        constexpr int NIT = (R * CPR) / NT;            // exact for all layers
        uint8_t* gbase = (uint8_t*)outp;
        #pragma unroll
        for (int it = 0; it < NIT; ++it) {
            const int c = it * NT + t;
            const int r = c / CPR, wi = c % CPR;
            const int p = wi / (COUT / 16), k = wi % (COUT / 16);
            const int gy = y0 + r, gx = cbase + p;
            if (gy < Wo && gx < Wo) {
                const uint8_t* src = (const uint8_t*)&outr[(r * 64 + p) * REC + k * 16];
                uint32_t v0 = *(const uint32_t*)(src + 0);
                uint32_t v1 = *(const uint32_t*)(src + 4);
                uint32_t v2 = *(const uint32_t*)(src + 8);
                uint32_t v3 = *(const uint32_t*)(src + 12);
                *(i32x4*)(gbase + (((size_t)n * Wo + gy) * Wo + gx) * COUT + k * 16)
                    = (i32x4){(int)v0, (int)v1, (int)v2, (int)v3};
            }
        }
    }
}

extern "C" void kernel_launch(void* const* d_in, const int* in_sizes, int n_in,
                              void* d_out, int out_size, void* d_ws, size_t ws_size,
                              hipStream_t stream) {
    const float* x  = (const float*)d_in[0];
    const float* w0 = (const float*)d_in[1];
    const float* w1 = (const float*)d_in[2];
    const float* w2 = (const float*)d_in[3];
    const float* w3 = (const float*)d_in[4];
    const float* w4 = (const float*)d_in[5];
    const float* w5 = (const float*)d_in[6];
    const float* w6 = (const float*)d_in[7];

    int8_t* A  = (int8_t*)d_ws;
    int8_t* B  = A + 58491136;
    int8_t* pA = B + 29984768;

    prepack_w<<<200, 256, 0, stream>>>(w3, w4, w5, w6, pA);

    // L0: (64,3,256,256) fp32 -> NHWC4 (64,127,127,4)
    conv0_pool_sign<<<4033, 256, 0, stream>>>(x, w0, (uint32_t*)A);
    // L1: NHWC4 -> NHWC8 (64,125,125,8)
    conv_l1<<<1000, 256, 0, stream>>>((const uint32_t*)A, w1, (uint2*)B);
    // L2: NHWC8 -> NHWC16 (64,123,123,16)
    conv_l2<<<954, 256, 0, stream>>>((const uint32_t*)B, w2, (i32x4*)A);

    // L3: 16->32, 123 -> 121.  R=8 (512 thr), CT=1, NMF=5
    conv_mfma<16, 32, 1, 8, 123, false><<<dim3(1, 16 * 2, 64), 512, 0, stream>>>(A, pA + 0, B, 121);
    // L4: 32->64, 121 -> 119.  R=4 (256 thr), CT=2, NMF=9
    conv_mfma<32, 64, 2, 4, 121, false><<<dim3(1, 30 * 2, 64), 256, 0, stream>>>(B, pA + 5120, A, 119);
    // L5: 64->32, 119 -> 117.  R=4 (256 thr), CT=1, NMF=18
    conv_mfma<64, 32, 1, 4, 119, false><<<dim3(1, 30 * 2, 64), 256, 0, stream>>>(A, pA + 23552, B, 117);
    // L6: 32->2, 117 -> 115, float NCHW out.  R=4, CT=1, NMF=9
    conv_mfma<32, 2, 1, 4, 117, true ><<<dim3(1, 29 * 2, 64), 256, 0, stream>>>(B, pA + 41984, d_out, 115);
}